// Round 14
// baseline (1778.831 us; speedup 1.0000x reference)
//
#include <hip/hip_runtime.h>
#include <hip/hip_bf16.h>
#include <math.h>

#define NL 4
#define TT 2048
#define DD 1024
#define KDIM 512
#define VDIM 1024
#define QSTR 3072     // fused qkvg row stride: q[0:512) k[512:1024) v[1024:2048) g[2048:3072)
#define NH 4
#define DKH 128
#define DVH 256
#define CH 64
#define NCH 32
#define VOCAB 32000
#define SCALE_Q 0.08838834764831845f

typedef short bf16x8 __attribute__((ext_vector_type(8)));
typedef float f32x4 __attribute__((ext_vector_type(4)));

__device__ __forceinline__ void gload_lds16(const void* g, void* l) {
    __builtin_amdgcn_global_load_lds((const __attribute__((address_space(1))) void*)g,
                                     (__attribute__((address_space(3))) void*)l, 16, 0, 0);
}

__device__ __forceinline__ void store_bf16x4(__hip_bfloat16* p, float a, float b, float c, float d) {
    union { __hip_bfloat16 h[4]; ushort4 v; } r;
    r.h[0] = __float2bfloat16(a); r.h[1] = __float2bfloat16(b);
    r.h[2] = __float2bfloat16(c); r.h[3] = __float2bfloat16(d);
    *(ushort4*)p = r.v;
}

// ---------------------------------------------------------------------------
// Shared swizzled-LDS primitives (proven 0-bank-conflict).
// Logical layout: 64B rows, row-pair packed into 128B lines:
//   logical byte of (row, cbyte) = (row>>1)*128 + (row&1)*64 + cbyte
//   physical = logical ^ (((logical>>7)&7)<<4)
// ---------------------------------------------------------------------------
__device__ __forceinline__ void swz_stage_chunk(const __hip_bfloat16* src, int row0,
                                                char* dst, int o, int lane, int kbase, int K) {
    int ob = o + lane * 16;
    int lg = ob ^ (((ob >> 7) & 7) << 4);
    int row = lg >> 6;
    int ce = (lg & 63) >> 1;
    gload_lds16(src + (size_t)(row0 + row) * K + kbase + ce, dst + o);
}

__device__ __forceinline__ bf16x8 swz_frag(const char* sub, int row, int lk2) {
    int lg = ((row >> 1) << 7) + ((row & 1) << 6) + lk2;
    return *(const bf16x8*)(sub + (lg ^ (((lg >> 7) & 7) << 4)));
}

// ---------------------------------------------------------------------------
// Embedding gather: h[t,:] = emb[ids[t],:] (f32 + bf16 copies)
// ---------------------------------------------------------------------------
__global__ __launch_bounds__(256) void embed_kernel(const int* __restrict__ ids,
                                                    const float* __restrict__ emb,
                                                    float* __restrict__ h,
                                                    __hip_bfloat16* __restrict__ hb) {
    int idx = blockIdx.x * 256 + threadIdx.x;      // TT*DD/4
    int t = idx >> 8, c4 = idx & 255;
    float4 v = *(const float4*)(emb + (size_t)ids[t] * DD + c4 * 4);
    *(float4*)(h + (size_t)t * DD + c4 * 4) = v;
    store_bf16x4(hb + (size_t)t * DD + c4 * 4, v.x, v.y, v.z, v.w);
}

// ---------------------------------------------------------------------------
// Transpose + convert: out[n][k] = bf16(in[k][n]).  in f32 [K][N]. grid (N/64, K/64)
// ---------------------------------------------------------------------------
__global__ __launch_bounds__(256) void tconv_kernel(const float* __restrict__ in,
                                                    __hip_bfloat16* __restrict__ out,
                                                    int K, int N) {
    __shared__ float tle[64][65];
    const int n0 = blockIdx.x * 64, k0 = blockIdx.y * 64;
    const int tid = threadIdx.x;
    const int ty = tid >> 4, tx = tid & 15;
#pragma unroll
    for (int u = 0; u < 4; u++) {
        int r = ty + u * 16;
        float4 v = *(const float4*)(in + (size_t)(k0 + r) * N + n0 + tx * 4);
        tle[r][tx * 4 + 0] = v.x; tle[r][tx * 4 + 1] = v.y;
        tle[r][tx * 4 + 2] = v.z; tle[r][tx * 4 + 3] = v.w;
    }
    __syncthreads();
#pragma unroll
    for (int u = 0; u < 4; u++) {
        int nn = u * 16 + ty;
        store_bf16x4(out + (size_t)(n0 + nn) * K + k0 + tx * 4,
                     tle[tx * 4 + 0][nn], tle[tx * 4 + 1][nn],
                     tle[tx * 4 + 2][nn], tle[tx * 4 + 3][nn]);
    }
}

// ---------------------------------------------------------------------------
// ALL per-layer weight transposes in one launch (4096 blocks = 4 layers x 1024).
// ---------------------------------------------------------------------------
__global__ __launch_bounds__(256) void tconv_all_kernel(const float* __restrict__ Wq,
                                                        const float* __restrict__ Wk,
                                                        const float* __restrict__ Wv,
                                                        const float* __restrict__ Wg,
                                                        const float* __restrict__ Wo,
                                                        __hip_bfloat16* __restrict__ Wt4,
                                                        __hip_bfloat16* __restrict__ WoT4) {
    __shared__ float tle[64][65];
    int l = blockIdx.x >> 10;
    int b = blockIdx.x & 1023;
    const float* wq = Wq + (size_t)l * DD * KDIM;
    const float* wk = Wk + (size_t)l * DD * KDIM;
    const float* wv = Wv + (size_t)l * DD * VDIM;
    const float* wg = Wg + (size_t)l * DD * VDIM;
    const float* wo = Wo + (size_t)l * VDIM * DD;
    __hip_bfloat16* Wt  = Wt4  + (size_t)l * QSTR * DD;
    __hip_bfloat16* WoT = WoT4 + (size_t)l * DD * VDIM;
    const float* src; __hip_bfloat16* dst; int N, local;
    if (b < 128)      { src = wq; dst = Wt;                         N = 512;  local = b; }
    else if (b < 256) { src = wk; dst = Wt + (size_t)512 * 1024;    N = 512;  local = b - 128; }
    else if (b < 512) { src = wv; dst = Wt + (size_t)1024 * 1024;   N = 1024; local = b - 256; }
    else if (b < 768) { src = wg; dst = Wt + (size_t)2048 * 1024;   N = 1024; local = b - 512; }
    else              { src = wo; dst = WoT;                        N = 1024; local = b - 768; }
    int nbx = N >> 6;
    int n0 = (local % nbx) * 64, k0 = (local / nbx) * 64;
    const int tid = threadIdx.x;
    const int ty = tid >> 4, tx = tid & 15;
#pragma unroll
    for (int u = 0; u < 4; u++) {
        int r = ty + u * 16;
        float4 v = *(const float4*)(src + (size_t)(k0 + r) * N + n0 + tx * 4);
        tle[r][tx * 4 + 0] = v.x; tle[r][tx * 4 + 1] = v.y;
        tle[r][tx * 4 + 2] = v.z; tle[r][tx * 4 + 3] = v.w;
    }
    __syncthreads();
#pragma unroll
    for (int u = 0; u < 4; u++) {
        int nn = u * 16 + ty;
        store_bf16x4(dst + (size_t)(n0 + nn) * 1024 + k0 + tx * 4,
                     tle[tx * 4 + 0][nn], tle[tx * 4 + 1][nn],
                     tle[tx * 4 + 2][nn], tle[tx * 4 + 3][nn]);
    }
}

// ---------------------------------------------------------------------------
// bf16 MFMA GEMM, double-buffered 2-phase: C[M,N](f32) = A[M,K] @ Bt[N,K]^T.
// 128 x (NF*32) tile, BK=32, 4 waves (2x2).  XCD-swizzled grid (nwg%8==0).
// Swizzled LDS (r13).
// ---------------------------------------------------------------------------
template<int NF>
__global__ __launch_bounds__(256) void gemm_bf16_db(const __hip_bfloat16* __restrict__ A,
                                                    const __hip_bfloat16* __restrict__ Bt,
                                                    const float* __restrict__ bias,
                                                    float* __restrict__ C,
                                                    __hip_bfloat16* __restrict__ Cb,
                                                    int M, int N, int K) {
    __shared__ __align__(16) char a_lds[2][8192];
    __shared__ __align__(16) char b_lds[2][NF * 2048];
    const int tid = threadIdx.x;
    const int wv = tid >> 6, lane = tid & 63;
    const int wr = wv >> 1, wc = wv & 1;
    const int nbx = gridDim.x;
    int wg = blockIdx.y * nbx + blockIdx.x;
    int cpx = (nbx * gridDim.y) >> 3;
    int swz = (wg & 7) * cpx + (wg >> 3);
    const int m0 = (swz % nbx) * 128, n0 = (swz / nbx) * (NF * 32);
    const int lr = lane & 15, lk2 = (lane >> 4) * 16;

    f32x4 acc[4][NF];
#pragma unroll
    for (int m = 0; m < 4; m++)
#pragma unroll
        for (int n = 0; n < NF; n++) acc[m][n] = (f32x4)(0.f);

    auto STAGE = [&](int buf, int k0) {
#pragma unroll
        for (int u = 0; u < 2; u++)
            swz_stage_chunk(A, m0, a_lds[buf], (wv * 2 + u) * 1024, lane, k0, K);
        if constexpr (NF == 4) {
#pragma unroll
            for (int u = 0; u < 2; u++)
                swz_stage_chunk(Bt, n0, b_lds[buf], (wv * 2 + u) * 1024, lane, k0, K);
        } else {
            swz_stage_chunk(Bt, n0, b_lds[buf], wv * 1024, lane, k0, K);
        }
    };
    auto COMPUTE = [&](int buf) {
        bf16x8 af[4], bfr[NF];
#pragma unroll
        for (int m = 0; m < 4; m++)
            af[m] = swz_frag(a_lds[buf], wr * 64 + m * 16 + lr, lk2);
#pragma unroll
        for (int n = 0; n < NF; n++)
            bfr[n] = swz_frag(b_lds[buf], wc * (NF * 16) + n * 16 + lr, lk2);
#pragma unroll
        for (int m = 0; m < 4; m++)
#pragma unroll
            for (int n = 0; n < NF; n++)
                acc[m][n] = __builtin_amdgcn_mfma_f32_16x16x32_bf16(af[m], bfr[n], acc[m][n], 0, 0, 0);
    };

    STAGE(0, 0);
    __syncthreads();
    int cur = 0;
    for (int k0 = 32; k0 < K; k0 += 32) {
        STAGE(cur ^ 1, k0);
        COMPUTE(cur);
        __syncthreads();
        cur ^= 1;
    }
    COMPUTE(cur);

    const int rbase = (lane >> 4) * 4;
#pragma unroll
    for (int n = 0; n < NF; n++) {
        int col = n0 + wc * (NF * 16) + n * 16 + lr;
        float bv = bias ? bias[col] : 0.f;
#pragma unroll
        for (int m = 0; m < 4; m++) {
            int row = m0 + wr * 64 + m * 16 + rbase;
#pragma unroll
            for (int r = 0; r < 4; r++) {
                float val = acc[m][n][r] + bv;
                C[(size_t)(row + r) * N + col] = val;
                if (Cb) Cb[(size_t)(row + r) * N + col] = __float2bfloat16(val);
            }
        }
    }
}

// ---------------------------------------------------------------------------
// 8-phase LM-head GEMM helpers.
// ---------------------------------------------------------------------------
__device__ __forceinline__ void lm_stage(const __hip_bfloat16* src, int row0,
                                         char* dst, int kt32, int wv, int lane, int K) {
#pragma unroll
    for (int ii = 0; ii < 2; ii++)
        swz_stage_chunk(src, row0, dst, (wv * 2 + ii) * 1024, lane, kt32 * 32, K);
}

// One phase: {frag ds_reads || stage 1 sub-tile} -> barrier -> setprio(1) +
// 16 MFMA + setprio(0) -> [vmcnt(4)] -> barrier.
// r14: m-quadrant is ROTATED per wave (mq = (PT + wv) & 3) so the 8 waves read
// 4 different A-row ranges in every phase and run de-phased ds_read/MFMA mixes
// (wave-stagger; each wave still covers all 4 quadrants per tile exactly once).
template<int PT, bool LOADB, int VM>
__device__ __forceinline__ void lm_phase(const char* aT, const char* bT,
                                         const __hip_bfloat16* ssrc, int srow0,
                                         char* sdst, int skt32,
                                         bf16x8 (&bfr)[4][2], f32x4 (&acc)[8][4],
                                         int wr, int wc, int lr, int lk2,
                                         int wv, int lane, int K) {
    const int mq = (PT + wv) & 3;          // wave-staggered quadrant
    if constexpr (LOADB) {
#pragma unroll
        for (int n = 0; n < 4; n++)
#pragma unroll
            for (int ks = 0; ks < 2; ks++)
                bfr[n][ks] = swz_frag(bT + ks * 16384, wc * 64 + n * 16 + lr, lk2);
    }
    bf16x8 af[2][2];
#pragma unroll
    for (int mm = 0; mm < 2; mm++)
#pragma unroll
        for (int ks = 0; ks < 2; ks++)
            af[mm][ks] = swz_frag(aT + ks * 16384, wr * 128 + (2 * mq + mm) * 16 + lr, lk2);
    lm_stage(ssrc, srow0, sdst, skt32, wv, lane, K);
    asm volatile("s_barrier" ::: "memory");
    __builtin_amdgcn_s_setprio(1);
#pragma unroll
    for (int mm = 0; mm < 2; mm++)
#pragma unroll
        for (int n = 0; n < 4; n++) {
            acc[2 * mq + mm][n] = __builtin_amdgcn_mfma_f32_16x16x32_bf16(af[mm][0], bfr[n][0], acc[2 * mq + mm][n], 0, 0, 0);
            acc[2 * mq + mm][n] = __builtin_amdgcn_mfma_f32_16x16x32_bf16(af[mm][1], bfr[n][1], acc[2 * mq + mm][n], 0, 0, 0);
        }
    __builtin_amdgcn_s_setprio(0);
    if constexpr (VM == 4) asm volatile("s_waitcnt vmcnt(4)" ::: "memory");
    asm volatile("s_barrier" ::: "memory");
}

// ---------------------------------------------------------------------------
// 256x256 LM-head GEMM, 8-phase schedule.  512 thr = 8 waves (2Mx4N),
// per-wave C = 128x64 (acc[8][4]).  BK=64/K-tile = 2 sub-tiles; 2 K-tiles/iter.
// LDS = 128KB: {sA0,sA1,sB0,sB1} x 32KB.
// vmcnt(4) PROOF (r10 induction): steady-state entry = 4 outstanding
// {B(2i+1)}; ph3 wait forces {B(2i+1),A(2i+1)} (read by ph4-7); ph7 wait
// forces {B(2i+2),A(2i+2)} (read by next ph0-3); never drains to 0.
// __launch_bounds__(512,1): acc = 128 f32/thread; tighter bound spills (r5).
// NT C-stores (r10 vs r12: keeps weights/WlmT resident in L3 across replays).
// ---------------------------------------------------------------------------
__global__ __launch_bounds__(512, 1) void gemm256_lm(const __hip_bfloat16* __restrict__ A,
                                                     const __hip_bfloat16* __restrict__ Bt,
                                                     const float* __restrict__ bias,
                                                     float* __restrict__ C,
                                                     int M, int N, int K) {
    extern __shared__ __align__(16) char smem[];
    char* sA0 = smem;
    char* sA1 = smem + 32768;
    char* sB0 = smem + 65536;
    char* sB1 = smem + 98304;
    const int tid = threadIdx.x;
    const int wv = tid >> 6, lane = tid & 63;
    const int wr = wv >> 2, wc = wv & 3;
    const int lr = lane & 15, lk2 = (lane >> 4) * 16;

    const int nbx = gridDim.x;
    int wg = blockIdx.y * nbx + blockIdx.x;
    int cpx = (nbx * gridDim.y) >> 3;
    int swz = (wg & 7) * cpx + (wg >> 3);
    const int m0 = (swz % nbx) * 256;
    const int n0 = (swz / nbx) * 256;

    f32x4 acc[8][4];
#pragma unroll
    for (int m = 0; m < 8; m++)
#pragma unroll
        for (int n = 0; n < 4; n++) acc[m][n] = (f32x4)(0.f);

    const int NTI = K / 64;
    const int NI  = NTI / 2;

    lm_stage(A,  m0, sA0 + 0,     0, wv, lane, K);
    lm_stage(A,  m0, sA0 + 16384, 1, wv, lane, K);
    lm_stage(Bt, n0, sB0 + 0,     0, wv, lane, K);
    lm_stage(Bt, n0, sB0 + 16384, 1, wv, lane, K);
    lm_stage(Bt, n0, sB1 + 0,     2, wv, lane, K);
    lm_stage(Bt, n0, sB1 + 16384, 3, wv, lane, K);
    asm volatile("s_waitcnt vmcnt(0)" ::: "memory");
    asm volatile("s_barrier" ::: "memory");

    for (int i = 0; i < NI; i++) {
        int tOdd = 2 * i + 1;
        int tE   = 2 * i + 2 < NTI ? 2 * i + 2 : NTI - 1;
        int tB3  = 2 * i + 3 < NTI ? 2 * i + 3 : NTI - 1;
        bf16x8 bfr[4][2];
        lm_phase<0, true , 0>(sA0, sB0, A,  m0, sA1 + 0,     2 * tOdd + 0, bfr, acc, wr, wc, lr, lk2, wv, lane, K);
        lm_phase<1, false, 0>(sA0, sB0, A,  m0, sA1 + 16384, 2 * tOdd + 1, bfr, acc, wr, wc, lr, lk2, wv, lane, K);
        lm_phase<2, false, 0>(sA0, sB0, Bt, n0, sB0 + 0,     2 * tE   + 0, bfr, acc, wr, wc, lr, lk2, wv, lane, K);
        lm_phase<3, false, 4>(sA0, sB0, Bt, n0, sB0 + 16384, 2 * tE   + 1, bfr, acc, wr, wc, lr, lk2, wv, lane, K);
        lm_phase<0, true , 0>(sA1, sB1, A,  m0, sA0 + 0,     2 * tE   + 0, bfr, acc, wr, wc, lr, lk2, wv, lane, K);
        lm_phase<1, false, 0>(sA1, sB1, A,  m0, sA0 + 16384, 2 * tE   + 1, bfr, acc, wr, wc, lr, lk2, wv, lane, K);
        lm_phase<2, false, 0>(sA1, sB1, Bt, n0, sB1 + 0,     2 * tB3  + 0, bfr, acc, wr, wc, lr, lk2, wv, lane, K);
        lm_phase<3, false, 4>(sA1, sB1, Bt, n0, sB1 + 16384, 2 * tB3  + 1, bfr, acc, wr, wc, lr, lk2, wv, lane, K);
    }

    const int r4 = (lane >> 4) * 4;
#pragma unroll
    for (int n = 0; n < 4; n++) {
        int col = n0 + wc * 64 + n * 16 + lr;
        float bv = bias ? bias[col] : 0.f;
#pragma unroll
        for (int m = 0; m < 8; m++) {
            int row = m0 + wr * 128 + m * 16 + r4;
#pragma unroll
            for (int r = 0; r < 4; r++)
                __builtin_nontemporal_store(acc[m][n][r] + bv,
                                            C + (size_t)(row + r) * N + col);
        }
    }
}

// ---------------------------------------------------------------------------
// Low-rank gate, stage 1: xg[t, j] = h[t, :] @ Wgk1[:, j]   (j < 16)
// ---------------------------------------------------------------------------
__global__ __launch_bounds__(256) void lowrank1_kernel(const float* __restrict__ h,
                                                       const float* __restrict__ W1,
                                                       float* __restrict__ xg) {
    int t = blockIdx.x;
    int tid = threadIdx.x;
    int j = tid & 15, ks = tid >> 4;
    const float* hr = h + (size_t)t * DD + ks * 64;
    const float* w = W1 + (size_t)(ks * 64) * 16 + j;
    float acc = 0.f;
#pragma unroll 8
    for (int kk = 0; kk < 64; kk++) acc = fmaf(hr[kk], w[kk * 16], acc);
    __shared__ float red[16][17];
    red[ks][j] = acc;
    __syncthreads();
    if (tid < 16) {
        float s = 0.f;
#pragma unroll
        for (int r = 0; r < 16; r++) s += red[r][tid];
        xg[t * 16 + tid] = s;
    }
}

// ---------------------------------------------------------------------------
// Fused gate pipeline (lowrank2 + gatescan).
// ---------------------------------------------------------------------------
__global__ __launch_bounds__(256) void gatefuse2_kernel(const float* __restrict__ qkvg,
                                                        const float* __restrict__ xg,
                                                        const float* __restrict__ W2,
                                                        const float* __restrict__ bg,
                                                        float* __restrict__ Gl,
                                                        __hip_bfloat16* __restrict__ qhB,
                                                        __hip_bfloat16* __restrict__ khB,
                                                        __hip_bfloat16* __restrict__ ktT) {
    __shared__ float w2s[16][64];
    __shared__ float xgs[64][16];
    __shared__ float part[4][64];
    const int tid = threadIdx.x;
    const int j = tid & 63, sg = tid >> 6;
    const int cg = blockIdx.x & 7, c = blockIdx.x >> 3;
    const int col = cg * 64 + j;
#pragma unroll
    for (int r = 0; r < 4; r++)
        w2s[sg * 4 + r][j] = W2[(size_t)(sg * 4 + r) * KDIM + col];
#pragma unroll
    for (int u = 0; u < 4; u++) {
        int id = u * 256 + tid;
        int t = id >> 4, r = id & 15;
        xgs[t][r] = xg[(size_t)(c * 64 + t) * 16 + r];
    }
    __syncthreads();
    const float bgv = bg[col];
    float ls[16];
    float partial = 0.f;
#pragma unroll
    for (int i = 0; i < 16; i++) {
        int t = sg * 16 + i;
        float s = bgv;
#pragma unroll
        for (int r = 0; r < 16; r++) s = fmaf(xgs[t][r], w2s[r][j], s);
        float v = (fminf(s, 0.f) - log1pf(expf(-fabsf(s)))) * (1.f / 16.f);
        ls[i] = v;
        partial += v;
    }
    part[sg][j] = partial;
    __syncthreads();
    float base = 0.f, total = 0.f;
#pragma unroll
    for (int r = 0; r < 4; r++) {
        float p = part[r][j];
        if (r < sg) base += p;
        total += p;
    }
    if (sg == 0) Gl[c * KDIM + col] = total;
    const float eGl = expf(total);
    const int hh = col >> 7, dk = col & 127;
    __hip_bfloat16 ktbuf[16];
    float G = base;
#pragma unroll
    for (int i = 0; i < 16; i++) {
        int t = c * 64 + sg * 16 + i;
        G += ls[i];
        const float* qp = qkvg + (size_t)t * QSTR + col;
        float qv = qp[0], kv = qp[512];
        qhB[(size_t)t * KDIM + col] = __float2bfloat16(qv * expf(G) * SCALE_Q);
        float khv = kv * expf(-G);
        khB[(size_t)t * KDIM + col] = __float2bfloat16(khv);
        ktbuf[i] = __float2bfloat16(khv * eGl);
    }
    __hip_bfloat16* kp = ktT + ((size_t)(c * NH + hh) * DKH + dk) * CH + sg * 16;
    *(uint4*)(kp + 0) = *(uint4*)&ktbuf[0];
    *(uint4*)(kp + 8) = *(uint4*)&ktbuf[8];
}

// ---------------------------------------------------------------------------
// v transpose to bf16: vT[c][h][dv][t'] = bf16(v[t0+t'][h*256+dv]).
// ---------------------------------------------------------------------------
__global__ __launch_bounds__(256) void vtrans_kernel(const float* __restrict__ qkvg,
                                                     __hip_bfloat16* __restrict__ vT) {
    __shared__ float tle[64][65];
    int bid = blockIdx.x;
    int dvq = bid & 3, hh = (bid >> 2) & 3, c = bid >> 4;
    int tid = threadIdx.x, ty = tid >> 4, tx = tid & 15;
#pragma unroll
    for (int u = 0; u < 4; u++) {
        int r = u * 16 + ty;
        float4 v = *(const float4*)(qkvg + (size_t)(c * 64 + r) * QSTR + 1024 + hh * DVH + dvq * 64 + tx * 4);
        tle[r][tx * 4 + 0] = v.x; tle[r][tx * 4 + 1] = v.y;
        tle[r][tx * 4 + 2] = v.z; tle[r][tx * 4 + 3] = v.w;
    }
    __syncthreads();
    __hip_bfloat16* dst = vT + ((size_t)(c * NH + hh) * DVH + dvq * 64) * CH;
#pragma unroll
    for (int u = 0; u < 4; u++) {
        int dv = u * 16 + ty;
        store_bf16x4(dst + (size_t)dv * CH + tx * 4,
                     tle[tx * 4 + 0][dv], tle[tx * 4 + 1][dv],
                     tle[tx * 4 + 2][dv], tle[tx * 4 + 3][dv]);
    }
}

// ---------------------------------------------------------------------------
// Chunk state contribution (transposed): U[c][h] (bf16 [256][128]) =
//   vT[c][h] @ ktT[c][h]^T.  r14: grid = NCH*NH*2 (dv-halves of 128 rows
//   each) so the dispatch fills all 256 CUs (was 128 blocks = half idle).
// ---------------------------------------------------------------------------
__global__ __launch_bounds__(256) void chunkU_mfma(const __hip_bfloat16* __restrict__ vT,
                                                   const __hip_bfloat16* __restrict__ ktT,
                                                   __hip_bfloat16* __restrict__ U) {
    const int h2 = blockIdx.x & 1;
    const int ch = blockIdx.x >> 1;
    const __hip_bfloat16* Ap = vT + (size_t)ch * DVH * CH + (size_t)h2 * 128 * CH;
    const __hip_bfloat16* Bp = ktT + (size_t)ch * DKH * CH;
    __hip_bfloat16* Cp = U + (size_t)ch * DVH * DKH + (size_t)h2 * 128 * DKH;
    const int tid = threadIdx.x, wv = tid >> 6, lane = tid & 63;
    const int wr = wv >> 1, wc = wv & 1;
    const int lr = lane & 15, lk = (lane >> 4) * 8;
    f32x4 acc[4][4];
#pragma unroll
    for (int m = 0; m < 4; m++)
#pragma unroll
        for (int n = 0; n < 4; n++) acc[m][n] = (f32x4)(0.f);
#pragma unroll
    for (int ks = 0; ks < 2; ks++) {
        bf16x8 a[4], b[4];
#pragma unroll
        for (int m = 0; m < 4; m++)
            a[m] = *(const bf16x8*)(Ap + (size_t)(wr * 64 + m * 16 + lr) * CH + ks * 32 + lk);
#pragma unroll
        for (int n = 0; n < 4; n++)
            b[n] = *(const bf16x8*)(Bp + (size_t)(wc * 64 + n * 16 + lr) * CH + ks * 32 + lk);
#pragma unroll
        for (int m = 0; m < 4; m++)
#pragma unroll
            for (int n = 0; n < 4; n++)
                acc[m][n] = __builtin_amdgcn_mfma_f32_16x16x32_bf16(a[m], b[n], acc[m][n], 0, 0, 0);
    }
    const int r4 = (lane >> 4) * 4;
#pragma unroll
    for (int m = 0; m < 4; m++)
#pragma unroll
        for (int n = 0; n < 4; n++)
#pragma unroll
            for (int r = 0; r < 4; r++)
                Cp[(size_t)(wr * 64 + m * 16 + r4 + r) * DKH + wc * 64 + n * 16 + lr] =
                    __float2bfloat16(acc[m][n][r]);
}

// ---------------------------------------------------------------------------
// State recurrence over chunks, in place on bf16 U (contrib -> state-before).
// ---------------------------------------------------------------------------
__global__ __launch_bounds__(256) void scan_states_kernel(__hip_bfloat16* __restrict__ U,
                                                          const float* __restrict__ Gl) {
    int idx = blockIdx.x * 256 + threadIdx.x;   // NH*DVH*DKH = 131072
    int hh = idx >> 15, dv = (idx >> 7) & 255, dk = idx & 127;
    int col = hh * DKH + dk;
    float s = 0.f;
    for (int c = 0; c < NCH; c++) {
        __hip_bfloat16* p = U + ((size_t)(c * NH + hh) * DVH + dv) * DKH + dk;
        float u = __bfloat162float(*p);
        *p = __float2bfloat16(s);
        s = s * expf(Gl[c * KDIM + col]) + u;
    }
}

// ---------------------------------------------------------------------------
// MFMA attention + fused RMSNorm*gnw*swish(g), writing obb bf16 directly.
// ---------------------------------------------------------------------------
__global__ __launch_bounds__(256) void attn_rms_mfma(const __hip_bfloat16* __restrict__ qhB,
                                                     const __hip_bfloat16* __restrict__ khB,
                                                     const __hip_bfloat16* __restrict__ vT,
                                                     const __hip_bfloat16* __restrict__ Ub,
                                                     const float* __restrict__ qkvg,
                                                     const float* __restrict__ nw,
                                                     __hip_bfloat16* __restrict__ obb) {
    __shared__ __hip_bfloat16 P[32 * 72];
    __shared__ float sums[32][2];
    const int bid = blockIdx.x;
    const int rh = bid & 1, hh = (bid >> 1) & 3, c = bid >> 3;
    const int t0 = c * CH;
    const int tid = threadIdx.x, wv = tid >> 6, lane = tid & 63;
    const int half = wv >> 1, rg = wv & 1;
    const int lr = lane & 15, lk = (lane >> 4) * 8;
    const int r4 = (lane >> 4) * 4;
    const int rr = rh * 32 + rg * 16;

    bf16x8 qf[4];
#pragma unroll
    for (int ks = 0; ks < 4; ks++)
        qf[ks] = *(const bf16x8*)(qhB + (size_t)(t0 + rr + lr) * KDIM + hh * DKH + ks * 32 + lk);

    if (half == 0) {
        f32x4 s[4];
#pragma unroll
        for (int n = 0; n < 4; n++) s[n] = (f32x4)(0.f);
#pragma unroll
        for (int n = 0; n < 4; n++)
#pragma unroll
            for (int ks = 0; ks < 4; ks++) {
                bf16x8 kf = *(const bf16x8*)(khB + (size_t)(t0 + n * 16 + lr) * KDIM + hh * DKH + ks * 32 + lk);
                s[n] = __builtin_amdgcn_mfma_f32_16x16x32_bf16(qf[ks], kf, s[n], 0, 0, 0);
            }
#pragma unroll
        for (int n = 0; n < 4; n++)
#pragma unroll
            for (int r = 0; r < 4; r++) {
                int i = rr + r4 + r, j = n * 16 + lr;
                float val = (j <= i) ? s[n][r] : 0.f;
                P[(rg * 16 + r4 + r) * 72 + j] = __float2bfloat16(val);
            }
    }
    __syncthreads();

    const __hip_bfloat16* vTp = vT + ((size_t)(c * NH + hh) * DVH + half * 128) * CH;
    const __hip_bfloat16* Ubp = Ub + ((size_t)(c * NH + hh) * DVH + half * 128) * DKH;
    bf16x8 pf[2];
#pragma unroll
    for (int ks = 0; ks < 2; ks++)
        pf[ks] = *(const bf16x8*)&P[(rg * 16 + lr) * 72 + ks * 32 + lk];

    f32x4 o[8];
#pragma unroll
    for (int n = 0; n < 8; n++) o[n] = (f32x4)(0.f);
#pragma unroll
    for (int n = 0; n < 8; n++) {
#pragma unroll
        for (int ks = 0; ks < 2; ks++) {
            bf16x8 vf = *(const bf16x8*)(vTp + (size_t)(n * 16 + lr) * CH + ks * 32 + lk);
            o[n] = __builtin_amdgcn_mfma_f32_16x16x32_bf16(pf[ks], vf, o[n], 0, 0, 0);
        }
#pragma unroll
        for (int ks = 0; ks < 4; ks++) {
            bf16x8 uf = *(const bf16x8*)(Ubp + (size_t)(n * 16 + lr) * DKH + ks * 32 + lk);
            o[n] = __builtin_amdgcn_mfma_f32_16x16x32_bf16(qf[ks], uf, o[n], 0, 0, 0);
        }
    }

    float part[4];
#pragma unroll
    for (int r = 0; r < 4; r++) {
        float p = 0.f;
#pragma unroll
        for (int n = 0; n < 8; n++) p = fmaf(o[n][r], o[n][r], p);
        part[r] = p;
    }
#pragma unroll
    for (int off = 1; off < 16; off <<= 1)
#pragma unroll
        for (int r = 0; r < 4; r++) part[r] += __shfl_xor(part[r], off);
    if (lr == 0)
#pragma unroll
        for (int r = 0; r < 4; r++) sums[rg * 16 + r4 + r][half] = part[r];
    __syncthreads();

#pragma unroll
    for (int r = 0; r < 4; r++) {
        int lrow = rg * 16 + r4 + r;
        int t = t0 + rh * 32 + lrow;
        float tot = sums[lrow][0] + sums[lrow][1];
        float rinv = rsqrtf(tot * (1.f / 256.f) + 1e-5f);
#pragma unroll
        for (int n = 0; n < 8; n++) {
            int col = half * 128 + n * 16 + lr;
            float gv = qkvg[(size_t)t * QSTR + 2048 + hh * DVH + col];
            float val = o[n][r] * rinv * nw[col] * (gv / (1.f + expf(-gv)));
            obb[(size_t)t * VDIM + hh * DVH + col] = __float2bfloat16(val);
        }
    }
}

// ---------------------------------------------------------------------------
// Final LayerNorm over D=1024 per row -> bf16
// ---------------------------------------------------------------------------
__global__ __launch_bounds__(256) void ln_kernel(const float* __restrict__ h,
                                                 const float* __restrict__ w,
                                                 const float* __restrict__ b,
                                                 __hip_bfloat16* __restrict__ out16) {
    int t = blockIdx.x;
    int tid = threadIdx.x;
    float4 x = *(const float4*)(h + (size_t)t * DD + tid * 4);
    float s = x.x + x.y + x.z + x.w;
    float ss = x.x * x.x + x.y * x.y + x.z * x.z + x.w * x.w;
#pragma unroll
    for (int off = 32; off > 0; off >>= 1) {
        s += __shfl_xor(s, off);
        ss += __shfl_xor(ss, off);
    }
    __shared__ float rs[4], rss[4];
    int wv = tid >> 6;
    if ((tid & 63) == 0) { rs[wv] = s; rss[wv] = ss; }
    __syncthreads();
    s = rs[0] + rs[1] + rs[2] + rs[3];
    ss = rss[0] + rss[1] + rss[2] + rss[3];
    float mu = s * (1.f / 1024.f);
    float var = ss * (1.f / 1024.f) - mu * mu;
    float r = rsqrtf(var + 1e-5f);
    float4 wv4 = *(const float4*)(w + tid * 4);
    float4 bv4 = *(const float4*)(b + tid * 4);
    store_bf16x4(out16 + (size_t)t * DD + tid * 4,
                 (x.x - mu) * r * wv4.x + bv4.x,
                 (x.y - mu) * r * wv4.y + bv4.y,
                 (x.z - mu) * r * wv4.z + bv4.z,
                 (x.w - mu) * r * wv4.w + bv4.w);
}

// ---------------------------------------------------------------------------
extern "C" void kernel_launch(void* const* d_in, const int* in_sizes, int n_in,
                              void* d_out, int out_size, void* d_ws, size_t ws_size,
                              hipStream_t stream) {
    const int*   ids  = (const int*)d_in[0];
    const float* emb  = (const float*)d_in[1];
    const float* Wq   = (const float*)d_in[2];
    const float* Wk   = (const float*)d_in[3];
    const float* Wv   = (const float*)d_in[4];
    const float* Wg   = (const float*)d_in[5];
    const float* Wgk1 = (const float*)d_in[6];
    const float* Wgk2 = (const float*)d_in[7];
    const float* bgk  = (const float*)d_in[8];
    const float* gnw  = (const float*)d_in[9];
    const float* Wo   = (const float*)d_in[10];
    const float* lnw  = (const float*)d_in[11];
    const float* lnb  = (const float*)d_in[12];
    const float* Wlm  = (const float*)d_in[13];
    const float* blm  = (const float*)d_in[14];
    float* out = (float*)d_out;

    float* ws = (float*)d_ws;
    float* h    = ws; ws += (size_t)TT * DD;        // 8MB
    float* qkvg = ws; ws += (size_t)TT * QSTR;      // 25MB
    float* xg   = ws; ws += (size_t)TT * 16;
    float* Gl   = ws; ws += (size_t)NCH * KDIM;
    __hip_bfloat16* hb    = (__hip_bfloat16*)ws; ws += (size_t)TT * DD / 2;     // 4MB
    __hip_bfloat16* obb   = (__hip_bfloat16*)ws; ws += (size_t)TT * DD / 2;
    __hip_bfloat16* lnb16 = (__hip_bfloat16*)ws; ws += (size_t)TT * DD / 2;
    __hip_bfloat16* qhB   = (__hip_bfloat16*)ws; ws += (size_t)TT * KDIM / 2;   // 2MB
    __hip_bfloat16* khB   = (__hip_bfloat16*)ws; ws += (size_t)TT * KDIM / 2;
    __hip_bfloat16* ktT   = (__hip_bfloat16*)ws; ws += (size_t)NCH * NH * DKH * CH / 2;  // 2MB
    __hip_bfloat16* vT    = (__hip_bfloat16*)ws; ws += (size_t)NCH * NH * DVH * CH / 2;  // 2MB
    __hip_bfloat16* Ub    = (__hip_bfloat16*)ws; ws += (size_t)NCH * NH * DVH * DKH / 2; // 8MB
    __hip_bfloat16* Wt4   = (__hip_bfloat16*)ws; ws += (size_t)NL * QSTR * DD / 2;  // 25MB
    __hip_bfloat16* WoT4  = (__hip_bfloat16*)ws; ws += (size_t)NL * DD * VDIM / 2;  // 8.4MB
    __hip_bfloat16* WlmT  = (__hip_bfloat16*)ws; ws += (size_t)VOCAB * DD / 2;      // 62.5MB

    hipFuncSetAttribute((const void*)gemm256_lm,
                        hipFuncAttributeMaxDynamicSharedMemorySize, 131072);

    embed_kernel<<<TT, 256, 0, stream>>>(ids, emb, h, hb);
    tconv_all_kernel<<<NL * 1024, 256, 0, stream>>>(Wq, Wk, Wv, Wg, Wo, Wt4, WoT4);
    tconv_kernel<<<dim3(VOCAB / 64, DD / 64), 256, 0, stream>>>(Wlm, WlmT, DD, VOCAB);

    for (int l = 0; l < NL; l++) {
        const float* w1 = Wgk1 + (size_t)l * DD * 16;
        const float* w2 = Wgk2 + (size_t)l * 16 * KDIM;
        const float* bg = bgk + (size_t)l * KDIM;
        const float* nw = gnw + (size_t)l * DVH;
        const __hip_bfloat16* Wt  = Wt4  + (size_t)l * QSTR * DD;
        const __hip_bfloat16* WoT = WoT4 + (size_t)l * DD * VDIM;

        gemm_bf16_db<4><<<dim3(TT / 128, QSTR / 128), 256, 0, stream>>>(hb, Wt, nullptr, qkvg, nullptr, TT, QSTR, DD);
        lowrank1_kernel<<<TT, 256, 0, stream>>>(h, w1, xg);
        gatefuse2_kernel<<<NCH * (KDIM / 64), 256, 0, stream>>>(qkvg, xg, w2, bg, Gl, qhB, khB, ktT);
        vtrans_kernel<<<NCH * NH * 4, 256, 0, stream>>>(qkvg, vT);
        chunkU_mfma<<<NCH * NH * 2, 256, 0, stream>>>(vT, ktT, Ub);
        scan_states_kernel<<<NH * DVH * DKH / 256, 256, 0, stream>>>(Ub, Gl);
        attn_rms_mfma<<<NCH * NH * 2, 256, 0, stream>>>(qhB, khB, vT, Ub, qkvg, nw, obb);
        gemm_bf16_db<2><<<dim3(TT / 128, DD / 64), 256, 0, stream>>>(obb, WoT, nullptr, h, hb, TT, DD, VDIM);
    }

    ln_kernel<<<TT, 256, 0, stream>>>(h, lnw, lnb, lnb16);
    gemm256_lm<<<dim3(TT / 256, VOCAB / 256), 512, 131072, stream>>>(lnb16, WlmT, blm, out, TT, VOCAB, DD);
}

// Round 15
// 641.895 us; speedup vs baseline: 2.7712x; 2.7712x over previous
//
#include <hip/hip_runtime.h>
#include <hip/hip_bf16.h>
#include <math.h>

#define NL 4
#define TT 2048
#define DD 1024
#define KDIM 512
#define VDIM 1024
#define QSTR 3072     // fused qkvg row stride: q[0:512) k[512:1024) v[1024:2048) g[2048:3072)
#define NH 4
#define DKH 128
#define DVH 256
#define CH 64
#define NCH 32
#define VOCAB 32000
#define SCALE_Q 0.08838834764831845f

typedef short bf16x8 __attribute__((ext_vector_type(8)));
typedef float f32x4 __attribute__((ext_vector_type(4)));

__device__ __forceinline__ void gload_lds16(const void* g, void* l) {
    __builtin_amdgcn_global_load_lds((const __attribute__((address_space(1))) void*)g,
                                     (__attribute__((address_space(3))) void*)l, 16, 0, 0);
}

__device__ __forceinline__ void store_bf16x4(__hip_bfloat16* p, float a, float b, float c, float d) {
    union { __hip_bfloat16 h[4]; ushort4 v; } r;
    r.h[0] = __float2bfloat16(a); r.h[1] = __float2bfloat16(b);
    r.h[2] = __float2bfloat16(c); r.h[3] = __float2bfloat16(d);
    *(ushort4*)p = r.v;
}

// ---------------------------------------------------------------------------
// Shared swizzled-LDS primitives (proven 0-bank-conflict).
// Logical layout: 64B rows, row-pair packed into 128B lines:
//   logical byte of (row, cbyte) = (row>>1)*128 + (row&1)*64 + cbyte
//   physical = logical ^ (((logical>>7)&7)<<4)
// ---------------------------------------------------------------------------
__device__ __forceinline__ void swz_stage_chunk(const __hip_bfloat16* src, int row0,
                                                char* dst, int o, int lane, int kbase, int K) {
    int ob = o + lane * 16;
    int lg = ob ^ (((ob >> 7) & 7) << 4);
    int row = lg >> 6;
    int ce = (lg & 63) >> 1;
    gload_lds16(src + (size_t)(row0 + row) * K + kbase + ce, dst + o);
}

__device__ __forceinline__ bf16x8 swz_frag(const char* sub, int row, int lk2) {
    int lg = ((row >> 1) << 7) + ((row & 1) << 6) + lk2;
    return *(const bf16x8*)(sub + (lg ^ (((lg >> 7) & 7) << 4)));
}

// ---------------------------------------------------------------------------
// Embedding gather: h[t,:] = emb[ids[t],:] (f32 + bf16 copies)
// ---------------------------------------------------------------------------
__global__ __launch_bounds__(256) void embed_kernel(const int* __restrict__ ids,
                                                    const float* __restrict__ emb,
                                                    float* __restrict__ h,
                                                    __hip_bfloat16* __restrict__ hb) {
    int idx = blockIdx.x * 256 + threadIdx.x;      // TT*DD/4
    int t = idx >> 8, c4 = idx & 255;
    float4 v = *(const float4*)(emb + (size_t)ids[t] * DD + c4 * 4);
    *(float4*)(h + (size_t)t * DD + c4 * 4) = v;
    store_bf16x4(hb + (size_t)t * DD + c4 * 4, v.x, v.y, v.z, v.w);
}

// ---------------------------------------------------------------------------
// Transpose + convert: out[n][k] = bf16(in[k][n]).  in f32 [K][N]. grid (N/64, K/64)
// ---------------------------------------------------------------------------
__global__ __launch_bounds__(256) void tconv_kernel(const float* __restrict__ in,
                                                    __hip_bfloat16* __restrict__ out,
                                                    int K, int N) {
    __shared__ float tle[64][65];
    const int n0 = blockIdx.x * 64, k0 = blockIdx.y * 64;
    const int tid = threadIdx.x;
    const int ty = tid >> 4, tx = tid & 15;
#pragma unroll
    for (int u = 0; u < 4; u++) {
        int r = ty + u * 16;
        float4 v = *(const float4*)(in + (size_t)(k0 + r) * N + n0 + tx * 4);
        tle[r][tx * 4 + 0] = v.x; tle[r][tx * 4 + 1] = v.y;
        tle[r][tx * 4 + 2] = v.z; tle[r][tx * 4 + 3] = v.w;
    }
    __syncthreads();
#pragma unroll
    for (int u = 0; u < 4; u++) {
        int nn = u * 16 + ty;
        store_bf16x4(out + (size_t)(n0 + nn) * K + k0 + tx * 4,
                     tle[tx * 4 + 0][nn], tle[tx * 4 + 1][nn],
                     tle[tx * 4 + 2][nn], tle[tx * 4 + 3][nn]);
    }
}

// ---------------------------------------------------------------------------
// ALL per-layer weight transposes in one launch (4096 blocks = 4 layers x 1024).
// ---------------------------------------------------------------------------
__global__ __launch_bounds__(256) void tconv_all_kernel(const float* __restrict__ Wq,
                                                        const float* __restrict__ Wk,
                                                        const float* __restrict__ Wv,
                                                        const float* __restrict__ Wg,
                                                        const float* __restrict__ Wo,
                                                        __hip_bfloat16* __restrict__ Wt4,
                                                        __hip_bfloat16* __restrict__ WoT4) {
    __shared__ float tle[64][65];
    int l = blockIdx.x >> 10;
    int b = blockIdx.x & 1023;
    const float* wq = Wq + (size_t)l * DD * KDIM;
    const float* wk = Wk + (size_t)l * DD * KDIM;
    const float* wv = Wv + (size_t)l * DD * VDIM;
    const float* wg = Wg + (size_t)l * DD * VDIM;
    const float* wo = Wo + (size_t)l * VDIM * DD;
    __hip_bfloat16* Wt  = Wt4  + (size_t)l * QSTR * DD;
    __hip_bfloat16* WoT = WoT4 + (size_t)l * DD * VDIM;
    const float* src; __hip_bfloat16* dst; int N, local;
    if (b < 128)      { src = wq; dst = Wt;                         N = 512;  local = b; }
    else if (b < 256) { src = wk; dst = Wt + (size_t)512 * 1024;    N = 512;  local = b - 128; }
    else if (b < 512) { src = wv; dst = Wt + (size_t)1024 * 1024;   N = 1024; local = b - 256; }
    else if (b < 768) { src = wg; dst = Wt + (size_t)2048 * 1024;   N = 1024; local = b - 512; }
    else              { src = wo; dst = WoT;                        N = 1024; local = b - 768; }
    int nbx = N >> 6;
    int n0 = (local % nbx) * 64, k0 = (local / nbx) * 64;
    const int tid = threadIdx.x;
    const int ty = tid >> 4, tx = tid & 15;
#pragma unroll
    for (int u = 0; u < 4; u++) {
        int r = ty + u * 16;
        float4 v = *(const float4*)(src + (size_t)(k0 + r) * N + n0 + tx * 4);
        tle[r][tx * 4 + 0] = v.x; tle[r][tx * 4 + 1] = v.y;
        tle[r][tx * 4 + 2] = v.z; tle[r][tx * 4 + 3] = v.w;
    }
    __syncthreads();
#pragma unroll
    for (int u = 0; u < 4; u++) {
        int nn = u * 16 + ty;
        store_bf16x4(dst + (size_t)(n0 + nn) * 1024 + k0 + tx * 4,
                     tle[tx * 4 + 0][nn], tle[tx * 4 + 1][nn],
                     tle[tx * 4 + 2][nn], tle[tx * 4 + 3][nn]);
    }
}

// ---------------------------------------------------------------------------
// bf16 MFMA GEMM, double-buffered 2-phase: C[M,N](f32) = A[M,K] @ Bt[N,K]^T.
// 128 x (NF*32) tile, BK=32, 4 waves (2x2).  XCD-swizzled grid (nwg%8==0).
// Swizzled LDS (r13).
// ---------------------------------------------------------------------------
template<int NF>
__global__ __launch_bounds__(256) void gemm_bf16_db(const __hip_bfloat16* __restrict__ A,
                                                    const __hip_bfloat16* __restrict__ Bt,
                                                    const float* __restrict__ bias,
                                                    float* __restrict__ C,
                                                    __hip_bfloat16* __restrict__ Cb,
                                                    int M, int N, int K) {
    __shared__ __align__(16) char a_lds[2][8192];
    __shared__ __align__(16) char b_lds[2][NF * 2048];
    const int tid = threadIdx.x;
    const int wv = tid >> 6, lane = tid & 63;
    const int wr = wv >> 1, wc = wv & 1;
    const int nbx = gridDim.x;
    int wg = blockIdx.y * nbx + blockIdx.x;
    int cpx = (nbx * gridDim.y) >> 3;
    int swz = (wg & 7) * cpx + (wg >> 3);
    const int m0 = (swz % nbx) * 128, n0 = (swz / nbx) * (NF * 32);
    const int lr = lane & 15, lk2 = (lane >> 4) * 16;

    f32x4 acc[4][NF];
#pragma unroll
    for (int m = 0; m < 4; m++)
#pragma unroll
        for (int n = 0; n < NF; n++) acc[m][n] = (f32x4)(0.f);

    auto STAGE = [&](int buf, int k0) {
#pragma unroll
        for (int u = 0; u < 2; u++)
            swz_stage_chunk(A, m0, a_lds[buf], (wv * 2 + u) * 1024, lane, k0, K);
        if constexpr (NF == 4) {
#pragma unroll
            for (int u = 0; u < 2; u++)
                swz_stage_chunk(Bt, n0, b_lds[buf], (wv * 2 + u) * 1024, lane, k0, K);
        } else {
            swz_stage_chunk(Bt, n0, b_lds[buf], wv * 1024, lane, k0, K);
        }
    };
    auto COMPUTE = [&](int buf) {
        bf16x8 af[4], bfr[NF];
#pragma unroll
        for (int m = 0; m < 4; m++)
            af[m] = swz_frag(a_lds[buf], wr * 64 + m * 16 + lr, lk2);
#pragma unroll
        for (int n = 0; n < NF; n++)
            bfr[n] = swz_frag(b_lds[buf], wc * (NF * 16) + n * 16 + lr, lk2);
#pragma unroll
        for (int m = 0; m < 4; m++)
#pragma unroll
            for (int n = 0; n < NF; n++)
                acc[m][n] = __builtin_amdgcn_mfma_f32_16x16x32_bf16(af[m], bfr[n], acc[m][n], 0, 0, 0);
    };

    STAGE(0, 0);
    __syncthreads();
    int cur = 0;
    for (int k0 = 32; k0 < K; k0 += 32) {
        STAGE(cur ^ 1, k0);
        COMPUTE(cur);
        __syncthreads();
        cur ^= 1;
    }
    COMPUTE(cur);

    const int rbase = (lane >> 4) * 4;
#pragma unroll
    for (int n = 0; n < NF; n++) {
        int col = n0 + wc * (NF * 16) + n * 16 + lr;
        float bv = bias ? bias[col] : 0.f;
#pragma unroll
        for (int m = 0; m < 4; m++) {
            int row = m0 + wr * 64 + m * 16 + rbase;
#pragma unroll
            for (int r = 0; r < 4; r++) {
                float val = acc[m][n][r] + bv;
                C[(size_t)(row + r) * N + col] = val;
                if (Cb) Cb[(size_t)(row + r) * N + col] = __float2bfloat16(val);
            }
        }
    }
}

// ---------------------------------------------------------------------------
// 8-phase LM-head GEMM helpers (r13 static-quadrant version; r14's runtime
// mq = (PT+wv)&3 violated rule #20 -- runtime-indexed acc -> scratch spill,
// 8x slowdown.  Quadrant index must be compile-time).
// ---------------------------------------------------------------------------
__device__ __forceinline__ void lm_stage(const __hip_bfloat16* src, int row0,
                                         char* dst, int kt32, int wv, int lane, int K) {
#pragma unroll
    for (int ii = 0; ii < 2; ii++)
        swz_stage_chunk(src, row0, dst, (wv * 2 + ii) * 1024, lane, kt32 * 32, K);
}

// One phase: {frag ds_reads || stage 1 sub-tile} -> barrier -> setprio(1) +
// 16 MFMA + setprio(0) -> [vmcnt(4)] -> barrier.  PT = m-quadrant (0..3).
template<int PT, bool LOADB, int VM>
__device__ __forceinline__ void lm_phase(const char* aT, const char* bT,
                                         const __hip_bfloat16* ssrc, int srow0,
                                         char* sdst, int skt32,
                                         bf16x8 (&bfr)[4][2], f32x4 (&acc)[8][4],
                                         int wr, int wc, int lr, int lk2,
                                         int wv, int lane, int K) {
    if constexpr (LOADB) {
#pragma unroll
        for (int n = 0; n < 4; n++)
#pragma unroll
            for (int ks = 0; ks < 2; ks++)
                bfr[n][ks] = swz_frag(bT + ks * 16384, wc * 64 + n * 16 + lr, lk2);
    }
    bf16x8 af[2][2];
#pragma unroll
    for (int mm = 0; mm < 2; mm++)
#pragma unroll
        for (int ks = 0; ks < 2; ks++)
            af[mm][ks] = swz_frag(aT + ks * 16384, wr * 128 + (2 * PT + mm) * 16 + lr, lk2);
    lm_stage(ssrc, srow0, sdst, skt32, wv, lane, K);
    asm volatile("s_barrier" ::: "memory");
    __builtin_amdgcn_s_setprio(1);
#pragma unroll
    for (int mm = 0; mm < 2; mm++)
#pragma unroll
        for (int n = 0; n < 4; n++) {
            acc[2 * PT + mm][n] = __builtin_amdgcn_mfma_f32_16x16x32_bf16(af[mm][0], bfr[n][0], acc[2 * PT + mm][n], 0, 0, 0);
            acc[2 * PT + mm][n] = __builtin_amdgcn_mfma_f32_16x16x32_bf16(af[mm][1], bfr[n][1], acc[2 * PT + mm][n], 0, 0, 0);
        }
    __builtin_amdgcn_s_setprio(0);
    if constexpr (VM == 4) asm volatile("s_waitcnt vmcnt(4)" ::: "memory");
    asm volatile("s_barrier" ::: "memory");
}

// ---------------------------------------------------------------------------
// 256x256 LM-head GEMM, 8-phase schedule.  512 thr = 8 waves (2Mx4N),
// per-wave C = 128x64 (acc[8][4]).  BK=64/K-tile = 2 sub-tiles; 2 K-tiles/iter.
// LDS = 128KB: {sA0,sA1,sB0,sB1} x 32KB.
// vmcnt(4) PROOF (r10 induction): steady-state entry = 4 outstanding
// {B(2i+1)}; ph3 wait forces {B(2i+1),A(2i+1)} (read by ph4-7); ph7 wait
// forces {B(2i+2),A(2i+2)} (read by next ph0-3); never drains to 0.
// __launch_bounds__(512,1): acc = 128 f32/thread; tighter bound spills (r5);
// runtime-indexed acc also spills (r14, rule #20).
// NT C-stores (r10 vs r12: keeps weights/WlmT resident in L3 across replays).
// ---------------------------------------------------------------------------
__global__ __launch_bounds__(512, 1) void gemm256_lm(const __hip_bfloat16* __restrict__ A,
                                                     const __hip_bfloat16* __restrict__ Bt,
                                                     const float* __restrict__ bias,
                                                     float* __restrict__ C,
                                                     int M, int N, int K) {
    extern __shared__ __align__(16) char smem[];
    char* sA0 = smem;
    char* sA1 = smem + 32768;
    char* sB0 = smem + 65536;
    char* sB1 = smem + 98304;
    const int tid = threadIdx.x;
    const int wv = tid >> 6, lane = tid & 63;
    const int wr = wv >> 2, wc = wv & 3;
    const int lr = lane & 15, lk2 = (lane >> 4) * 16;

    const int nbx = gridDim.x;
    int wg = blockIdx.y * nbx + blockIdx.x;
    int cpx = (nbx * gridDim.y) >> 3;
    int swz = (wg & 7) * cpx + (wg >> 3);
    const int m0 = (swz % nbx) * 256;
    const int n0 = (swz / nbx) * 256;

    f32x4 acc[8][4];
#pragma unroll
    for (int m = 0; m < 8; m++)
#pragma unroll
        for (int n = 0; n < 4; n++) acc[m][n] = (f32x4)(0.f);

    const int NTI = K / 64;
    const int NI  = NTI / 2;

    lm_stage(A,  m0, sA0 + 0,     0, wv, lane, K);
    lm_stage(A,  m0, sA0 + 16384, 1, wv, lane, K);
    lm_stage(Bt, n0, sB0 + 0,     0, wv, lane, K);
    lm_stage(Bt, n0, sB0 + 16384, 1, wv, lane, K);
    lm_stage(Bt, n0, sB1 + 0,     2, wv, lane, K);
    lm_stage(Bt, n0, sB1 + 16384, 3, wv, lane, K);
    asm volatile("s_waitcnt vmcnt(0)" ::: "memory");
    asm volatile("s_barrier" ::: "memory");

    for (int i = 0; i < NI; i++) {
        int tOdd = 2 * i + 1;
        int tE   = 2 * i + 2 < NTI ? 2 * i + 2 : NTI - 1;
        int tB3  = 2 * i + 3 < NTI ? 2 * i + 3 : NTI - 1;
        bf16x8 bfr[4][2];
        lm_phase<0, true , 0>(sA0, sB0, A,  m0, sA1 + 0,     2 * tOdd + 0, bfr, acc, wr, wc, lr, lk2, wv, lane, K);
        lm_phase<1, false, 0>(sA0, sB0, A,  m0, sA1 + 16384, 2 * tOdd + 1, bfr, acc, wr, wc, lr, lk2, wv, lane, K);
        lm_phase<2, false, 0>(sA0, sB0, Bt, n0, sB0 + 0,     2 * tE   + 0, bfr, acc, wr, wc, lr, lk2, wv, lane, K);
        lm_phase<3, false, 4>(sA0, sB0, Bt, n0, sB0 + 16384, 2 * tE   + 1, bfr, acc, wr, wc, lr, lk2, wv, lane, K);
        lm_phase<0, true , 0>(sA1, sB1, A,  m0, sA0 + 0,     2 * tE   + 0, bfr, acc, wr, wc, lr, lk2, wv, lane, K);
        lm_phase<1, false, 0>(sA1, sB1, A,  m0, sA0 + 16384, 2 * tE   + 1, bfr, acc, wr, wc, lr, lk2, wv, lane, K);
        lm_phase<2, false, 0>(sA1, sB1, Bt, n0, sB1 + 0,     2 * tB3  + 0, bfr, acc, wr, wc, lr, lk2, wv, lane, K);
        lm_phase<3, false, 4>(sA1, sB1, Bt, n0, sB1 + 16384, 2 * tB3  + 1, bfr, acc, wr, wc, lr, lk2, wv, lane, K);
    }

    const int r4 = (lane >> 4) * 4;
#pragma unroll
    for (int n = 0; n < 4; n++) {
        int col = n0 + wc * 64 + n * 16 + lr;
        float bv = bias ? bias[col] : 0.f;
#pragma unroll
        for (int m = 0; m < 8; m++) {
            int row = m0 + wr * 128 + m * 16 + r4;
#pragma unroll
            for (int r = 0; r < 4; r++)
                __builtin_nontemporal_store(acc[m][n][r] + bv,
                                            C + (size_t)(row + r) * N + col);
        }
    }
}

// ---------------------------------------------------------------------------
// Low-rank gate, stage 1: xg[t, j] = h[t, :] @ Wgk1[:, j]   (j < 16)
// ---------------------------------------------------------------------------
__global__ __launch_bounds__(256) void lowrank1_kernel(const float* __restrict__ h,
                                                       const float* __restrict__ W1,
                                                       float* __restrict__ xg) {
    int t = blockIdx.x;
    int tid = threadIdx.x;
    int j = tid & 15, ks = tid >> 4;
    const float* hr = h + (size_t)t * DD + ks * 64;
    const float* w = W1 + (size_t)(ks * 64) * 16 + j;
    float acc = 0.f;
#pragma unroll 8
    for (int kk = 0; kk < 64; kk++) acc = fmaf(hr[kk], w[kk * 16], acc);
    __shared__ float red[16][17];
    red[ks][j] = acc;
    __syncthreads();
    if (tid < 16) {
        float s = 0.f;
#pragma unroll
        for (int r = 0; r < 16; r++) s += red[r][tid];
        xg[t * 16 + tid] = s;
    }
}

// ---------------------------------------------------------------------------
// Fused gate pipeline (lowrank2 + gatescan).
// ---------------------------------------------------------------------------
__global__ __launch_bounds__(256) void gatefuse2_kernel(const float* __restrict__ qkvg,
                                                        const float* __restrict__ xg,
                                                        const float* __restrict__ W2,
                                                        const float* __restrict__ bg,
                                                        float* __restrict__ Gl,
                                                        __hip_bfloat16* __restrict__ qhB,
                                                        __hip_bfloat16* __restrict__ khB,
                                                        __hip_bfloat16* __restrict__ ktT) {
    __shared__ float w2s[16][64];
    __shared__ float xgs[64][16];
    __shared__ float part[4][64];
    const int tid = threadIdx.x;
    const int j = tid & 63, sg = tid >> 6;
    const int cg = blockIdx.x & 7, c = blockIdx.x >> 3;
    const int col = cg * 64 + j;
#pragma unroll
    for (int r = 0; r < 4; r++)
        w2s[sg * 4 + r][j] = W2[(size_t)(sg * 4 + r) * KDIM + col];
#pragma unroll
    for (int u = 0; u < 4; u++) {
        int id = u * 256 + tid;
        int t = id >> 4, r = id & 15;
        xgs[t][r] = xg[(size_t)(c * 64 + t) * 16 + r];
    }
    __syncthreads();
    const float bgv = bg[col];
    float ls[16];
    float partial = 0.f;
#pragma unroll
    for (int i = 0; i < 16; i++) {
        int t = sg * 16 + i;
        float s = bgv;
#pragma unroll
        for (int r = 0; r < 16; r++) s = fmaf(xgs[t][r], w2s[r][j], s);
        float v = (fminf(s, 0.f) - log1pf(expf(-fabsf(s)))) * (1.f / 16.f);
        ls[i] = v;
        partial += v;
    }
    part[sg][j] = partial;
    __syncthreads();
    float base = 0.f, total = 0.f;
#pragma unroll
    for (int r = 0; r < 4; r++) {
        float p = part[r][j];
        if (r < sg) base += p;
        total += p;
    }
    if (sg == 0) Gl[c * KDIM + col] = total;
    const float eGl = expf(total);
    const int hh = col >> 7, dk = col & 127;
    __hip_bfloat16 ktbuf[16];
    float G = base;
#pragma unroll
    for (int i = 0; i < 16; i++) {
        int t = c * 64 + sg * 16 + i;
        G += ls[i];
        const float* qp = qkvg + (size_t)t * QSTR + col;
        float qv = qp[0], kv = qp[512];
        qhB[(size_t)t * KDIM + col] = __float2bfloat16(qv * expf(G) * SCALE_Q);
        float khv = kv * expf(-G);
        khB[(size_t)t * KDIM + col] = __float2bfloat16(khv);
        ktbuf[i] = __float2bfloat16(khv * eGl);
    }
    __hip_bfloat16* kp = ktT + ((size_t)(c * NH + hh) * DKH + dk) * CH + sg * 16;
    *(uint4*)(kp + 0) = *(uint4*)&ktbuf[0];
    *(uint4*)(kp + 8) = *(uint4*)&ktbuf[8];
}

// ---------------------------------------------------------------------------
// v transpose to bf16: vT[c][h][dv][t'] = bf16(v[t0+t'][h*256+dv]).
// ---------------------------------------------------------------------------
__global__ __launch_bounds__(256) void vtrans_kernel(const float* __restrict__ qkvg,
                                                     __hip_bfloat16* __restrict__ vT) {
    __shared__ float tle[64][65];
    int bid = blockIdx.x;
    int dvq = bid & 3, hh = (bid >> 2) & 3, c = bid >> 4;
    int tid = threadIdx.x, ty = tid >> 4, tx = tid & 15;
#pragma unroll
    for (int u = 0; u < 4; u++) {
        int r = u * 16 + ty;
        float4 v = *(const float4*)(qkvg + (size_t)(c * 64 + r) * QSTR + 1024 + hh * DVH + dvq * 64 + tx * 4);
        tle[r][tx * 4 + 0] = v.x; tle[r][tx * 4 + 1] = v.y;
        tle[r][tx * 4 + 2] = v.z; tle[r][tx * 4 + 3] = v.w;
    }
    __syncthreads();
    __hip_bfloat16* dst = vT + ((size_t)(c * NH + hh) * DVH + dvq * 64) * CH;
#pragma unroll
    for (int u = 0; u < 4; u++) {
        int dv = u * 16 + ty;
        store_bf16x4(dst + (size_t)dv * CH + tx * 4,
                     tle[tx * 4 + 0][dv], tle[tx * 4 + 1][dv],
                     tle[tx * 4 + 2][dv], tle[tx * 4 + 3][dv]);
    }
}

// ---------------------------------------------------------------------------
// Chunk state contribution (transposed): U[c][h] (bf16 [256][128]) =
//   vT[c][h] @ ktT[c][h]^T.  grid = NCH*NH*2 (dv-halves; fills all 256 CUs).
// ---------------------------------------------------------------------------
__global__ __launch_bounds__(256) void chunkU_mfma(const __hip_bfloat16* __restrict__ vT,
                                                   const __hip_bfloat16* __restrict__ ktT,
                                                   __hip_bfloat16* __restrict__ U) {
    const int h2 = blockIdx.x & 1;
    const int ch = blockIdx.x >> 1;
    const __hip_bfloat16* Ap = vT + (size_t)ch * DVH * CH + (size_t)h2 * 128 * CH;
    const __hip_bfloat16* Bp = ktT + (size_t)ch * DKH * CH;
    __hip_bfloat16* Cp = U + (size_t)ch * DVH * DKH + (size_t)h2 * 128 * DKH;
    const int tid = threadIdx.x, wv = tid >> 6, lane = tid & 63;
    const int wr = wv >> 1, wc = wv & 1;
    const int lr = lane & 15, lk = (lane >> 4) * 8;
    f32x4 acc[4][4];
#pragma unroll
    for (int m = 0; m < 4; m++)
#pragma unroll
        for (int n = 0; n < 4; n++) acc[m][n] = (f32x4)(0.f);
#pragma unroll
    for (int ks = 0; ks < 2; ks++) {
        bf16x8 a[4], b[4];
#pragma unroll
        for (int m = 0; m < 4; m++)
            a[m] = *(const bf16x8*)(Ap + (size_t)(wr * 64 + m * 16 + lr) * CH + ks * 32 + lk);
#pragma unroll
        for (int n = 0; n < 4; n++)
            b[n] = *(const bf16x8*)(Bp + (size_t)(wc * 64 + n * 16 + lr) * CH + ks * 32 + lk);
#pragma unroll
        for (int m = 0; m < 4; m++)
#pragma unroll
            for (int n = 0; n < 4; n++)
                acc[m][n] = __builtin_amdgcn_mfma_f32_16x16x32_bf16(a[m], b[n], acc[m][n], 0, 0, 0);
    }
    const int r4 = (lane >> 4) * 4;
#pragma unroll
    for (int m = 0; m < 4; m++)
#pragma unroll
        for (int n = 0; n < 4; n++)
#pragma unroll
            for (int r = 0; r < 4; r++)
                Cp[(size_t)(wr * 64 + m * 16 + r4 + r) * DKH + wc * 64 + n * 16 + lr] =
                    __float2bfloat16(acc[m][n][r]);
}

// ---------------------------------------------------------------------------
// State recurrence over chunks, in place on bf16 U (contrib -> state-before).
// ---------------------------------------------------------------------------
__global__ __launch_bounds__(256) void scan_states_kernel(__hip_bfloat16* __restrict__ U,
                                                          const float* __restrict__ Gl) {
    int idx = blockIdx.x * 256 + threadIdx.x;   // NH*DVH*DKH = 131072
    int hh = idx >> 15, dv = (idx >> 7) & 255, dk = idx & 127;
    int col = hh * DKH + dk;
    float s = 0.f;
    for (int c = 0; c < NCH; c++) {
        __hip_bfloat16* p = U + ((size_t)(c * NH + hh) * DVH + dv) * DKH + dk;
        float u = __bfloat162float(*p);
        *p = __float2bfloat16(s);
        s = s * expf(Gl[c * KDIM + col]) + u;
    }
}

// ---------------------------------------------------------------------------
// MFMA attention + fused RMSNorm*gnw*swish(g), writing obb bf16 directly.
// ---------------------------------------------------------------------------
__global__ __launch_bounds__(256) void attn_rms_mfma(const __hip_bfloat16* __restrict__ qhB,
                                                     const __hip_bfloat16* __restrict__ khB,
                                                     const __hip_bfloat16* __restrict__ vT,
                                                     const __hip_bfloat16* __restrict__ Ub,
                                                     const float* __restrict__ qkvg,
                                                     const float* __restrict__ nw,
                                                     __hip_bfloat16* __restrict__ obb) {
    __shared__ __hip_bfloat16 P[32 * 72];
    __shared__ float sums[32][2];
    const int bid = blockIdx.x;
    const int rh = bid & 1, hh = (bid >> 1) & 3, c = bid >> 3;
    const int t0 = c * CH;
    const int tid = threadIdx.x, wv = tid >> 6, lane = tid & 63;
    const int half = wv >> 1, rg = wv & 1;
    const int lr = lane & 15, lk = (lane >> 4) * 8;
    const int r4 = (lane >> 4) * 4;
    const int rr = rh * 32 + rg * 16;

    bf16x8 qf[4];
#pragma unroll
    for (int ks = 0; ks < 4; ks++)
        qf[ks] = *(const bf16x8*)(qhB + (size_t)(t0 + rr + lr) * KDIM + hh * DKH + ks * 32 + lk);

    if (half == 0) {
        f32x4 s[4];
#pragma unroll
        for (int n = 0; n < 4; n++) s[n] = (f32x4)(0.f);
#pragma unroll
        for (int n = 0; n < 4; n++)
#pragma unroll
            for (int ks = 0; ks < 4; ks++) {
                bf16x8 kf = *(const bf16x8*)(khB + (size_t)(t0 + n * 16 + lr) * KDIM + hh * DKH + ks * 32 + lk);
                s[n] = __builtin_amdgcn_mfma_f32_16x16x32_bf16(qf[ks], kf, s[n], 0, 0, 0);
            }
#pragma unroll
        for (int n = 0; n < 4; n++)
#pragma unroll
            for (int r = 0; r < 4; r++) {
                int i = rr + r4 + r, j = n * 16 + lr;
                float val = (j <= i) ? s[n][r] : 0.f;
                P[(rg * 16 + r4 + r) * 72 + j] = __float2bfloat16(val);
            }
    }
    __syncthreads();

    const __hip_bfloat16* vTp = vT + ((size_t)(c * NH + hh) * DVH + half * 128) * CH;
    const __hip_bfloat16* Ubp = Ub + ((size_t)(c * NH + hh) * DVH + half * 128) * DKH;
    bf16x8 pf[2];
#pragma unroll
    for (int ks = 0; ks < 2; ks++)
        pf[ks] = *(const bf16x8*)&P[(rg * 16 + lr) * 72 + ks * 32 + lk];

    f32x4 o[8];
#pragma unroll
    for (int n = 0; n < 8; n++) o[n] = (f32x4)(0.f);
#pragma unroll
    for (int n = 0; n < 8; n++) {
#pragma unroll
        for (int ks = 0; ks < 2; ks++) {
            bf16x8 vf = *(const bf16x8*)(vTp + (size_t)(n * 16 + lr) * CH + ks * 32 + lk);
            o[n] = __builtin_amdgcn_mfma_f32_16x16x32_bf16(pf[ks], vf, o[n], 0, 0, 0);
        }
#pragma unroll
        for (int ks = 0; ks < 4; ks++) {
            bf16x8 uf = *(const bf16x8*)(Ubp + (size_t)(n * 16 + lr) * DKH + ks * 32 + lk);
            o[n] = __builtin_amdgcn_mfma_f32_16x16x32_bf16(qf[ks], uf, o[n], 0, 0, 0);
        }
    }

    float part[4];
#pragma unroll
    for (int r = 0; r < 4; r++) {
        float p = 0.f;
#pragma unroll
        for (int n = 0; n < 8; n++) p = fmaf(o[n][r], o[n][r], p);
        part[r] = p;
    }
#pragma unroll
    for (int off = 1; off < 16; off <<= 1)
#pragma unroll
        for (int r = 0; r < 4; r++) part[r] += __shfl_xor(part[r], off);
    if (lr == 0)
#pragma unroll
        for (int r = 0; r < 4; r++) sums[rg * 16 + r4 + r][half] = part[r];
    __syncthreads();

#pragma unroll
    for (int r = 0; r < 4; r++) {
        int lrow = rg * 16 + r4 + r;
        int t = t0 + rh * 32 + lrow;
        float tot = sums[lrow][0] + sums[lrow][1];
        float rinv = rsqrtf(tot * (1.f / 256.f) + 1e-5f);
#pragma unroll
        for (int n = 0; n < 8; n++) {
            int col = half * 128 + n * 16 + lr;
            float gv = qkvg[(size_t)t * QSTR + 2048 + hh * DVH + col];
            float val = o[n][r] * rinv * nw[col] * (gv / (1.f + expf(-gv)));
            obb[(size_t)t * VDIM + hh * DVH + col] = __float2bfloat16(val);
        }
    }
}

// ---------------------------------------------------------------------------
// Final LayerNorm over D=1024 per row -> bf16
// ---------------------------------------------------------------------------
__global__ __launch_bounds__(256) void ln_kernel(const float* __restrict__ h,
                                                 const float* __restrict__ w,
                                                 const float* __restrict__ b,
                                                 __hip_bfloat16* __restrict__ out16) {
    int t = blockIdx.x;
    int tid = threadIdx.x;
    float4 x = *(const float4*)(h + (size_t)t * DD + tid * 4);
    float s = x.x + x.y + x.z + x.w;
    float ss = x.x * x.x + x.y * x.y + x.z * x.z + x.w * x.w;
#pragma unroll
    for (int off = 32; off > 0; off >>= 1) {
        s += __shfl_xor(s, off);
        ss += __shfl_xor(ss, off);
    }
    __shared__ float rs[4], rss[4];
    int wv = tid >> 6;
    if ((tid & 63) == 0) { rs[wv] = s; rss[wv] = ss; }
    __syncthreads();
    s = rs[0] + rs[1] + rs[2] + rs[3];
    ss = rss[0] + rss[1] + rss[2] + rss[3];
    float mu = s * (1.f / 1024.f);
    float var = ss * (1.f / 1024.f) - mu * mu;
    float r = rsqrtf(var + 1e-5f);
    float4 wv4 = *(const float4*)(w + tid * 4);
    float4 bv4 = *(const float4*)(b + tid * 4);
    store_bf16x4(out16 + (size_t)t * DD + tid * 4,
                 (x.x - mu) * r * wv4.x + bv4.x,
                 (x.y - mu) * r * wv4.y + bv4.y,
                 (x.z - mu) * r * wv4.z + bv4.z,
                 (x.w - mu) * r * wv4.w + bv4.w);
}

// ---------------------------------------------------------------------------
extern "C" void kernel_launch(void* const* d_in, const int* in_sizes, int n_in,
                              void* d_out, int out_size, void* d_ws, size_t ws_size,
                              hipStream_t stream) {
    const int*   ids  = (const int*)d_in[0];
    const float* emb  = (const float*)d_in[1];
    const float* Wq   = (const float*)d_in[2];
    const float* Wk   = (const float*)d_in[3];
    const float* Wv   = (const float*)d_in[4];
    const float* Wg   = (const float*)d_in[5];
    const float* Wgk1 = (const float*)d_in[6];
    const float* Wgk2 = (const float*)d_in[7];
    const float* bgk  = (const float*)d_in[8];
    const float* gnw  = (const float*)d_in[9];
    const float* Wo   = (const float*)d_in[10];
    const float* lnw  = (const float*)d_in[11];
    const float* lnb  = (const float*)d_in[12];
    const float* Wlm  = (const float*)d_in[13];
    const float* blm  = (const float*)d_in[14];
    float* out = (float*)d_out;

    float* ws = (float*)d_ws;
    float* h    = ws; ws += (size_t)TT * DD;        // 8MB
    float* qkvg = ws; ws += (size_t)TT * QSTR;      // 25MB
    float* xg   = ws; ws += (size_t)TT * 16;
    float* Gl   = ws; ws += (size_t)NCH * KDIM;
    __hip_bfloat16* hb    = (__hip_bfloat16*)ws; ws += (size_t)TT * DD / 2;     // 4MB
    __hip_bfloat16* obb   = (__hip_bfloat16*)ws; ws += (size_t)TT * DD / 2;
    __hip_bfloat16* lnb16 = (__hip_bfloat16*)ws; ws += (size_t)TT * DD / 2;
    __hip_bfloat16* qhB   = (__hip_bfloat16*)ws; ws += (size_t)TT * KDIM / 2;   // 2MB
    __hip_bfloat16* khB   = (__hip_bfloat16*)ws; ws += (size_t)TT * KDIM / 2;
    __hip_bfloat16* ktT   = (__hip_bfloat16*)ws; ws += (size_t)NCH * NH * DKH * CH / 2;  // 2MB
    __hip_bfloat16* vT    = (__hip_bfloat16*)ws; ws += (size_t)NCH * NH * DVH * CH / 2;  // 2MB
    __hip_bfloat16* Ub    = (__hip_bfloat16*)ws; ws += (size_t)NCH * NH * DVH * DKH / 2; // 8MB
    __hip_bfloat16* Wt4   = (__hip_bfloat16*)ws; ws += (size_t)NL * QSTR * DD / 2;  // 25MB
    __hip_bfloat16* WoT4  = (__hip_bfloat16*)ws; ws += (size_t)NL * DD * VDIM / 2;  // 8.4MB
    __hip_bfloat16* WlmT  = (__hip_bfloat16*)ws; ws += (size_t)VOCAB * DD / 2;      // 62.5MB

    hipFuncSetAttribute((const void*)gemm256_lm,
                        hipFuncAttributeMaxDynamicSharedMemorySize, 131072);

    embed_kernel<<<TT, 256, 0, stream>>>(ids, emb, h, hb);
    tconv_all_kernel<<<NL * 1024, 256, 0, stream>>>(Wq, Wk, Wv, Wg, Wo, Wt4, WoT4);
    tconv_kernel<<<dim3(VOCAB / 64, DD / 64), 256, 0, stream>>>(Wlm, WlmT, DD, VOCAB);

    for (int l = 0; l < NL; l++) {
        const float* w1 = Wgk1 + (size_t)l * DD * 16;
        const float* w2 = Wgk2 + (size_t)l * 16 * KDIM;
        const float* bg = bgk + (size_t)l * KDIM;
        const float* nw = gnw + (size_t)l * DVH;
        const __hip_bfloat16* Wt  = Wt4  + (size_t)l * QSTR * DD;
        const __hip_bfloat16* WoT = WoT4 + (size_t)l * DD * VDIM;

        gemm_bf16_db<4><<<dim3(TT / 128, QSTR / 128), 256, 0, stream>>>(hb, Wt, nullptr, qkvg, nullptr, TT, QSTR, DD);
        lowrank1_kernel<<<TT, 256, 0, stream>>>(h, w1, xg);
        gatefuse2_kernel<<<NCH * (KDIM / 64), 256, 0, stream>>>(qkvg, xg, w2, bg, Gl, qhB, khB, ktT);
        vtrans_kernel<<<NCH * NH * 4, 256, 0, stream>>>(qkvg, vT);
        chunkU_mfma<<<NCH * NH * 2, 256, 0, stream>>>(vT, ktT, Ub);
        scan_states_kernel<<<NH * DVH * DKH / 256, 256, 0, stream>>>(Ub, Gl);
        attn_rms_mfma<<<NCH * NH * 2, 256, 0, stream>>>(qhB, khB, vT, Ub, qkvg, nw, obb);
        gemm_bf16_db<2><<<dim3(TT / 128, DD / 64), 256, 0, stream>>>(obb, WoT, nullptr, h, hb, TT, DD, VDIM);
    }

    ln_kernel<<<TT, 256, 0, stream>>>(h, lnw, lnb, lnb16);
    gemm256_lm<<<dim3(TT / 256, VOCAB / 256), 512, 131072, stream>>>(lnb16, WlmT, blm, out, TT, VOCAB, DD);
}